// Round 7
// baseline (466.711 us; speedup 1.0000x reference)
//
#include <hip/hip_runtime.h>
#include <hip/hip_bf16.h>

typedef __bf16 bf16;
typedef __bf16 bf16x4 __attribute__((ext_vector_type(4)));
typedef __bf16 bf16x8 __attribute__((ext_vector_type(8)));
typedef float  f32x4  __attribute__((ext_vector_type(4)));

#define AS1 __attribute__((address_space(1)))
#define AS3 __attribute__((address_space(3)))

__device__ __forceinline__ void gload_lds16(const bf16* g, bf16* l) {
    __builtin_amdgcn_global_load_lds((const AS1 void*)g, (AS3 void*)l, 16, 0, 0);
}

__device__ __forceinline__ void stage8_f32(const float* s, bf16* l) {
    float4 a = *(const float4*)s;
    float4 b = *(const float4*)(s + 4);
    bf16x8 o;
    o[0] = (bf16)a.x; o[1] = (bf16)a.y; o[2] = (bf16)a.z; o[3] = (bf16)a.w;
    o[4] = (bf16)b.x; o[5] = (bf16)b.y; o[6] = (bf16)b.z; o[7] = (bf16)b.w;
    *(bf16x8*)l = o;
}

// ---------------------------------------------------------------------------
// 128x128 GEMM tile core: acc += A[M,K] @ B[N,K]^T (bf16 MFMA). bf16 sources
// use async global_load_lds (m97 path); fp32 sources stage via VGPR convert.
// ---------------------------------------------------------------------------
template <bool AF32, bool BF32>
__device__ __forceinline__ void gemm_core(
    const void* __restrict__ Av, const void* __restrict__ Bv,
    int m0, int n0, int K, f32x4 (&acc)[4][4],
    int wm, int wn, int r16, int q8)
{
    constexpr int LDA = AF32 ? 40 : 32;
    constexpr int LDB = BF32 ? 40 : 32;
    __shared__ __align__(16) bf16 As[128 * LDA];
    __shared__ __align__(16) bf16 Bs[128 * LDB];

    const int tid = threadIdx.x;
    const int i0 = tid, i1 = tid + 256;
    const int r0 = i0 >> 2, c0 = (i0 & 3) * 8;
    const int r1 = i1 >> 2, c1 = (i1 & 3) * 8;
    const size_t a0 = (size_t)(m0 + r0) * K + c0, a1 = (size_t)(m0 + r1) * K + c1;
    const size_t b0 = (size_t)(n0 + r0) * K + c0, b1 = (size_t)(n0 + r1) * K + c1;

    for (int k0 = 0; k0 < K; k0 += 32) {
        if constexpr (AF32) {
            stage8_f32((const float*)Av + a0 + k0, &As[r0 * LDA + c0]);
            stage8_f32((const float*)Av + a1 + k0, &As[r1 * LDA + c1]);
        } else {
            gload_lds16((const bf16*)Av + a0 + k0, &As[i0 * 8]);
            gload_lds16((const bf16*)Av + a1 + k0, &As[i1 * 8]);
        }
        if constexpr (BF32) {
            stage8_f32((const float*)Bv + b0 + k0, &Bs[r0 * LDB + c0]);
            stage8_f32((const float*)Bv + b1 + k0, &Bs[r1 * LDB + c1]);
        } else {
            gload_lds16((const bf16*)Bv + b0 + k0, &Bs[i0 * 8]);
            gload_lds16((const bf16*)Bv + b1 + k0, &Bs[i1 * 8]);
        }
        __syncthreads();

        bf16x8 a[4], b[4];
#pragma unroll
        for (int r = 0; r < 4; ++r)
            a[r] = *(const bf16x8*)&As[(wm + r * 16 + r16) * LDA + q8 * 8];
#pragma unroll
        for (int c = 0; c < 4; ++c)
            b[c] = *(const bf16x8*)&Bs[(wn + c * 16 + r16) * LDB + q8 * 8];
#pragma unroll
        for (int r = 0; r < 4; ++r)
#pragma unroll
            for (int c = 0; c < 4; ++c)
                acc[r][c] = __builtin_amdgcn_mfma_f32_16x16x32_bf16(a[r], b[c], acc[r][c], 0, 0, 0);
        __syncthreads();
    }
}

// ---------------------------------------------------------------------------
// fp32 -> bf16 bulk convert: y selects {x, Wq, Wlk, Wlv, Wo}.
// ---------------------------------------------------------------------------
__global__ __launch_bounds__(256) void cvt5(
    const float* __restrict__ s0, const float* __restrict__ s1,
    const float* __restrict__ s2, const float* __restrict__ s3,
    const float* __restrict__ s4,
    bf16* __restrict__ d0, bf16* __restrict__ d1, bf16* __restrict__ d2,
    bf16* __restrict__ d3, bf16* __restrict__ d4)
{
    const float* S[5] = {s0, s1, s2, s3, s4};
    bf16*        D[5] = {d0, d1, d2, d3, d4};
    const int    N[5] = {4194304, 4194304, 1048576, 1048576, 4194304};
    int y = blockIdx.y;
    int base = (blockIdx.x * 256 + threadIdx.x) * 8;
    if (base >= N[y]) return;
    stage8_f32(S[y] + base, D[y] + base);
}

// ---------------------------------------------------------------------------
// Projections: grid=(24,16); bx<16 -> Q (natural), 16..19 -> LK (natural),
// 20..23 -> LV stored TRANSPOSED as LVt[hd=512][T=2048] (b64-packed: the 4
// accumulator regs are consecutive t-rows).
// ---------------------------------------------------------------------------
template <bool F32>
__global__ __launch_bounds__(256) void proj_kernel_t(
    const void* __restrict__ x, const void* __restrict__ Wq,
    const void* __restrict__ Wlk, const void* __restrict__ Wlv,
    bf16* __restrict__ Q, bf16* __restrict__ LK, bf16* __restrict__ LVt)
{
    const int bx = blockIdx.x, by = blockIdx.y;
    const int tid = threadIdx.x, lane = tid & 63, wave = tid >> 6;
    const int wm = (wave >> 1) * 64, wn = (wave & 1) * 64;
    const int r16 = lane & 15, q8 = lane >> 4;
    f32x4 acc[4][4] = {};

    const void* Bv; int n0;
    if (bx < 16)      { Bv = Wq;  n0 = bx * 128; }
    else if (bx < 20) { Bv = Wlk; n0 = (bx - 16) * 128; }
    else              { Bv = Wlv; n0 = (bx - 20) * 128; }

    gemm_core<F32, F32>(x, Bv, by * 128, n0, 2048, acc, wm, wn, r16, q8);

    if (bx < 20) {
        bf16* C  = (bx < 16) ? Q : LK;
        int ldc  = (bx < 16) ? 2048 : 512;
#pragma unroll
        for (int r = 0; r < 4; ++r)
#pragma unroll
            for (int c = 0; c < 4; ++c)
#pragma unroll
                for (int i = 0; i < 4; ++i) {
                    int row = by * 128 + wm + r * 16 + q8 * 4 + i;
                    int col = n0 + wn + c * 16 + r16;
                    C[(size_t)row * ldc + col] = (bf16)acc[r][c][i];
                }
    } else {
#pragma unroll
        for (int r = 0; r < 4; ++r)
#pragma unroll
            for (int c = 0; c < 4; ++c) {
                int hd = n0 + wn + c * 16 + r16;
                int tb = by * 128 + wm + r * 16 + q8 * 4;
                bf16x4 pk;
#pragma unroll
                for (int i = 0; i < 4; ++i) pk[i] = (bf16)acc[r][c][i];
                *(bf16x4*)&LVt[(size_t)hd * 2048 + tb] = pk;
            }
    }
}

// Output GEMM: out = ATT(bf16) @ Wo^T -> fp32 d_out. grid=(16,16).
template <bool BF32>
__global__ __launch_bounds__(256) void out_kernel_t(
    const bf16* __restrict__ A, const void* __restrict__ Wo, float* __restrict__ C)
{
    const int tid = threadIdx.x, lane = tid & 63, wave = tid >> 6;
    const int wm = (wave >> 1) * 64, wn = (wave & 1) * 64;
    const int r16 = lane & 15, q8 = lane >> 4;
    f32x4 acc[4][4] = {};
    gemm_core<false, BF32>(A, Wo, blockIdx.y * 128, blockIdx.x * 128, 2048, acc, wm, wn, r16, q8);
#pragma unroll
    for (int r = 0; r < 4; ++r)
#pragma unroll
        for (int c = 0; c < 4; ++c)
#pragma unroll
            for (int i = 0; i < 4; ++i) {
                int row = blockIdx.y * 128 + wm + r * 16 + q8 * 4 + i;
                int col = blockIdx.x * 128 + wn + c * 16 + r16;
                C[(size_t)row * 2048 + col] = acc[r][c][i];
            }
}

// ---------------------------------------------------------------------------
// Attention v2. grid=(32,64): x = 64-row t block, y = h*4+g.
// S^T = K·Q^T (A=K, B=Q) so each lane's 4 accs are consecutive s -> b64-packed
// Ps write. K/V/Q fragments load straight from global (no intra-block reuse;
// L2 serves cross-block reuse). Ps (LD=72) is wave-private -> NO barriers.
// ---------------------------------------------------------------------------
__global__ __launch_bounds__(256) void attn2(
    const bf16* __restrict__ Q, const bf16* __restrict__ LK,
    const bf16* __restrict__ LVt, bf16* __restrict__ O)
{
    __shared__ __align__(16) bf16 Ps[64 * 72];

    const int tid  = threadIdx.x;
    const int lane = tid & 63;
    const int w    = tid >> 6;
    const int r16  = lane & 15;
    const int q8   = lane >> 4;
    const int hg = blockIdx.y, h = hg >> 2, g = hg & 3;
    const int t0 = blockIdx.x * 64;

    // loop-invariant Q B-fragment: B[n=t][k=d]
    const bf16x8 qb = *(const bf16x8*)(Q + (size_t)(t0 + w * 16 + r16) * 2048
                                       + h * 128 + g * 32 + q8 * 8);
    const bf16* Kb = LK + h * 32 + q8 * 8;
    const bf16* Vb = LVt + (size_t)(h * 32) * 2048;

    f32x4 o_acc[2] = {};
    float lsum = 0.f;
    // exp(s/sqrt(128)) == exp2(s * C)
    const float C = 0.08838834764831845f * 1.4426950408889634f;
    const f32x4 z = {0.f, 0.f, 0.f, 0.f};

    for (int sb = 0; sb < 2048; sb += 64) {
        f32x4 s[4];
#pragma unroll
        for (int c = 0; c < 4; ++c) {
            bf16x8 kb = *(const bf16x8*)(Kb + (size_t)(sb + c * 16 + r16) * 512);
            s[c] = __builtin_amdgcn_mfma_f32_16x16x32_bf16(kb, qb, z, 0, 0, 0);
        }
        // lane holds S[t = w*16+r16][s = c*16+q8*4+i] -> exp, pack, b64 write
#pragma unroll
        for (int c = 0; c < 4; ++c) {
            bf16x4 pk;
#pragma unroll
            for (int i = 0; i < 4; ++i) {
                float p = exp2f(s[c][i] * C);
                lsum += p;
                pk[i] = (bf16)p;
            }
            *(bf16x4*)&Ps[(w * 16 + r16) * 72 + c * 16 + q8 * 4] = pk;
        }
        // O += P @ V^T : A = P rows (wave-private strip), B = LVt rows
#pragma unroll
        for (int kk = 0; kk < 2; ++kk) {
            bf16x8 ap = *(const bf16x8*)&Ps[(w * 16 + r16) * 72 + kk * 32 + q8 * 8];
#pragma unroll
            for (int ct = 0; ct < 2; ++ct) {
                bf16x8 vb = *(const bf16x8*)(Vb + (size_t)(ct * 16 + r16) * 2048
                                             + sb + kk * 32 + q8 * 8);
                o_acc[ct] = __builtin_amdgcn_mfma_f32_16x16x32_bf16(ap, vb, o_acc[ct], 0, 0, 0);
            }
        }
    }

    // full row-sum for t = w*16 + r16 (reduce over the q8 groups)
    lsum += __shfl_xor(lsum, 16);
    lsum += __shfl_xor(lsum, 32);
    // O C-layout rows are t_local = q8*4+i -> fetch sums from lanes r16'=q8*4+i
    float ls[4];
#pragma unroll
    for (int i = 0; i < 4; ++i) ls[i] = __shfl(lsum, q8 * 4 + i);

#pragma unroll
    for (int ct = 0; ct < 2; ++ct)
#pragma unroll
        for (int i = 0; i < 4; ++i) {
            float o = o_acc[ct][i] / ls[i];
            int t = t0 + w * 16 + q8 * 4 + i;
            int d = ct * 16 + r16;
            O[(size_t)t * 2048 + h * 128 + g * 32 + d] = (bf16)o;
        }
}

// ---------------------------------------------------------------------------
// Contract (verified R5): inputs fp32, output fp32. Fast path (ws>=24MB):
// cvt to bf16 (xb/Wqb scratch inside d_out, dead before out_gemm writes it),
// async-staged GEMMs. Fallback (ws>=12MB): fp32-VGPR-staged GEMMs (R5-style).
// ---------------------------------------------------------------------------
extern "C" void kernel_launch(void* const* d_in, const int* in_sizes, int n_in,
                              void* d_out, int out_size, void* d_ws, size_t ws_size,
                              hipStream_t stream) {
    const float* x   = (const float*)d_in[0];
    const float* Wq  = (const float*)d_in[1];
    // d_in[2]=Wk, d_in[3]=Wv: computed-but-unused in the reference -> skipped
    const float* Wlk = (const float*)d_in[4];
    const float* Wlv = (const float*)d_in[5];
    const float* Wo  = (const float*)d_in[6];
    float* out = (float*)d_out;

    const size_t M4 = 4194304, M1 = 1048576;
    const size_t need_fast = (M1 + M1 + M4 + M4 + M1 + M1) * 2;  // 24 MB

    if (ws_size >= need_fast) {
        bf16* xb   = (bf16*)d_out;      // 8 MB  (d_out = 16 MB, dead before out_gemm)
        bf16* Wqb  = xb + M4;           // 8 MB
        bf16* p    = (bf16*)d_ws;
        bf16* Wlkb = p; p += M1;
        bf16* Wlvb = p; p += M1;
        bf16* Wob  = p; p += M4;
        bf16* Qp   = p; p += M4;
        bf16* LKp  = p; p += M1;
        bf16* LVt  = p;
        bf16* ATT  = Qp;                // alias: attn block reads its own Q cells first

        cvt5<<<dim3(2048, 5), 256, 0, stream>>>(x, Wq, Wlk, Wlv, Wo,
                                                xb, Wqb, Wlkb, Wlvb, Wob);
        proj_kernel_t<false><<<dim3(24, 16), 256, 0, stream>>>(xb, Wqb, Wlkb, Wlvb,
                                                               Qp, LKp, LVt);
        attn2<<<dim3(32, 64), 256, 0, stream>>>(Qp, LKp, LVt, ATT);
        out_kernel_t<false><<<dim3(16, 16), 256, 0, stream>>>(ATT, Wob, out);
    } else {
        bf16* Qp  = (bf16*)d_ws;        // 8 MB
        bf16* LKp = Qp + M4;            // 2 MB
        bf16* LVt = LKp + M1;           // 2 MB
        bf16* ATT = Qp;

        proj_kernel_t<true><<<dim3(24, 16), 256, 0, stream>>>(x, Wq, Wlk, Wlv,
                                                              Qp, LKp, LVt);
        attn2<<<dim3(32, 64), 256, 0, stream>>>(Qp, LKp, LVt, ATT);
        out_kernel_t<true><<<dim3(16, 16), 256, 0, stream>>>(ATT, Wo, out);
    }
}

// Round 8
// 304.525 us; speedup vs baseline: 1.5326x; 1.5326x over previous
//
#include <hip/hip_runtime.h>
#include <hip/hip_bf16.h>

typedef __bf16 bf16;
typedef __bf16 bf16x4 __attribute__((ext_vector_type(4)));
typedef __bf16 bf16x8 __attribute__((ext_vector_type(8)));
typedef float  f32x4  __attribute__((ext_vector_type(4)));

#define AS1 __attribute__((address_space(1)))
#define AS3 __attribute__((address_space(3)))

__device__ __forceinline__ void gload_lds16(const bf16* g, bf16* l) {
    __builtin_amdgcn_global_load_lds((const AS1 void*)g, (AS3 void*)l, 16, 0, 0);
}

__device__ __forceinline__ void stage8_f32(const float* s, bf16* l) {
    float4 a = *(const float4*)s;
    float4 b = *(const float4*)(s + 4);
    bf16x8 o;
    o[0] = (bf16)a.x; o[1] = (bf16)a.y; o[2] = (bf16)a.z; o[3] = (bf16)a.w;
    o[4] = (bf16)b.x; o[5] = (bf16)b.y; o[6] = (bf16)b.z; o[7] = (bf16)b.w;
    *(bf16x8*)l = o;
}

// ---------------------------------------------------------------------------
// 128x128 GEMM tile core: acc += A[M,K] @ B[N,K]^T (bf16 MFMA).
// ---------------------------------------------------------------------------
template <bool AF32, bool BF32>
__device__ __forceinline__ void gemm_core(
    const void* __restrict__ Av, const void* __restrict__ Bv,
    int m0, int n0, int K, f32x4 (&acc)[4][4],
    int wm, int wn, int r16, int q8)
{
    constexpr int LDA = AF32 ? 40 : 32;
    constexpr int LDB = BF32 ? 40 : 32;
    __shared__ __align__(16) bf16 As[128 * LDA];
    __shared__ __align__(16) bf16 Bs[128 * LDB];

    const int tid = threadIdx.x;
    const int i0 = tid, i1 = tid + 256;
    const int r0 = i0 >> 2, c0 = (i0 & 3) * 8;
    const int r1 = i1 >> 2, c1 = (i1 & 3) * 8;
    const size_t a0 = (size_t)(m0 + r0) * K + c0, a1 = (size_t)(m0 + r1) * K + c1;
    const size_t b0 = (size_t)(n0 + r0) * K + c0, b1 = (size_t)(n0 + r1) * K + c1;

    for (int k0 = 0; k0 < K; k0 += 32) {
        if constexpr (AF32) {
            stage8_f32((const float*)Av + a0 + k0, &As[r0 * LDA + c0]);
            stage8_f32((const float*)Av + a1 + k0, &As[r1 * LDA + c1]);
        } else {
            gload_lds16((const bf16*)Av + a0 + k0, &As[i0 * 8]);
            gload_lds16((const bf16*)Av + a1 + k0, &As[i1 * 8]);
        }
        if constexpr (BF32) {
            stage8_f32((const float*)Bv + b0 + k0, &Bs[r0 * LDB + c0]);
            stage8_f32((const float*)Bv + b1 + k0, &Bs[r1 * LDB + c1]);
        } else {
            gload_lds16((const bf16*)Bv + b0 + k0, &Bs[i0 * 8]);
            gload_lds16((const bf16*)Bv + b1 + k0, &Bs[i1 * 8]);
        }
        __syncthreads();

        bf16x8 a[4], b[4];
#pragma unroll
        for (int r = 0; r < 4; ++r)
            a[r] = *(const bf16x8*)&As[(wm + r * 16 + r16) * LDA + q8 * 8];
#pragma unroll
        for (int c = 0; c < 4; ++c)
            b[c] = *(const bf16x8*)&Bs[(wn + c * 16 + r16) * LDB + q8 * 8];
#pragma unroll
        for (int r = 0; r < 4; ++r)
#pragma unroll
            for (int c = 0; c < 4; ++c)
                acc[r][c] = __builtin_amdgcn_mfma_f32_16x16x32_bf16(a[r], b[c], acc[r][c], 0, 0, 0);
        __syncthreads();
    }
}

// fp32 -> bf16 bulk convert: y selects {x, Wq, Wlk, Wlv, Wo}.
__global__ __launch_bounds__(256) void cvt5(
    const float* __restrict__ s0, const float* __restrict__ s1,
    const float* __restrict__ s2, const float* __restrict__ s3,
    const float* __restrict__ s4,
    bf16* __restrict__ d0, bf16* __restrict__ d1, bf16* __restrict__ d2,
    bf16* __restrict__ d3, bf16* __restrict__ d4)
{
    const float* S[5] = {s0, s1, s2, s3, s4};
    bf16*        D[5] = {d0, d1, d2, d3, d4};
    const int    N[5] = {4194304, 4194304, 1048576, 1048576, 4194304};
    int y = blockIdx.y;
    int base = (blockIdx.x * 256 + threadIdx.x) * 8;
    if (base >= N[y]) return;
    stage8_f32(S[y] + base, D[y] + base);
}

// ---------------------------------------------------------------------------
// Projections: grid=(24,16); bx<16 -> Q, 16..19 -> LK, 20..23 -> LV stored
// TRANSPOSED as LVt[hd=512][T=2048] (b64-packed epilogue).
// ---------------------------------------------------------------------------
template <bool F32>
__global__ __launch_bounds__(256) void proj_kernel_t(
    const void* __restrict__ x, const void* __restrict__ Wq,
    const void* __restrict__ Wlk, const void* __restrict__ Wlv,
    bf16* __restrict__ Q, bf16* __restrict__ LK, bf16* __restrict__ LVt)
{
    const int bx = blockIdx.x, by = blockIdx.y;
    const int tid = threadIdx.x, lane = tid & 63, wave = tid >> 6;
    const int wm = (wave >> 1) * 64, wn = (wave & 1) * 64;
    const int r16 = lane & 15, q8 = lane >> 4;
    f32x4 acc[4][4] = {};

    const void* Bv; int n0;
    if (bx < 16)      { Bv = Wq;  n0 = bx * 128; }
    else if (bx < 20) { Bv = Wlk; n0 = (bx - 16) * 128; }
    else              { Bv = Wlv; n0 = (bx - 20) * 128; }

    gemm_core<F32, F32>(x, Bv, by * 128, n0, 2048, acc, wm, wn, r16, q8);

    if (bx < 20) {
        bf16* C  = (bx < 16) ? Q : LK;
        int ldc  = (bx < 16) ? 2048 : 512;
#pragma unroll
        for (int r = 0; r < 4; ++r)
#pragma unroll
            for (int c = 0; c < 4; ++c)
#pragma unroll
                for (int i = 0; i < 4; ++i) {
                    int row = by * 128 + wm + r * 16 + q8 * 4 + i;
                    int col = n0 + wn + c * 16 + r16;
                    C[(size_t)row * ldc + col] = (bf16)acc[r][c][i];
                }
    } else {
#pragma unroll
        for (int r = 0; r < 4; ++r)
#pragma unroll
            for (int c = 0; c < 4; ++c) {
                int hd = n0 + wn + c * 16 + r16;
                int tb = by * 128 + wm + r * 16 + q8 * 4;
                bf16x4 pk;
#pragma unroll
                for (int i = 0; i < 4; ++i) pk[i] = (bf16)acc[r][c][i];
                *(bf16x4*)&LVt[(size_t)hd * 2048 + tb] = pk;
            }
    }
}

// Output GEMM: out = ATT(bf16) @ Wo^T -> fp32 d_out. grid=(16,16).
template <bool BF32>
__global__ __launch_bounds__(256) void out_kernel_t(
    const bf16* __restrict__ A, const void* __restrict__ Wo, float* __restrict__ C)
{
    const int tid = threadIdx.x, lane = tid & 63, wave = tid >> 6;
    const int wm = (wave >> 1) * 64, wn = (wave & 1) * 64;
    const int r16 = lane & 15, q8 = lane >> 4;
    f32x4 acc[4][4] = {};
    gemm_core<false, BF32>(A, Wo, blockIdx.y * 128, blockIdx.x * 128, 2048, acc, wm, wn, r16, q8);
#pragma unroll
    for (int r = 0; r < 4; ++r)
#pragma unroll
        for (int c = 0; c < 4; ++c)
#pragma unroll
            for (int i = 0; i < 4; ++i) {
                int row = blockIdx.y * 128 + wm + r * 16 + q8 * 4 + i;
                int col = blockIdx.x * 128 + wn + c * 16 + r16;
                C[(size_t)row * 2048 + col] = acc[r][c][i];
            }
}

// ---------------------------------------------------------------------------
// Attention v3: LDS-staged K/V (coalesced gload_lds16) with XOR-swizzled
// layouts (<=2-way bank aliasing, free per m136) + wave-private packed Ps.
// grid=(32,64): x = 64-row t block, y = h*4+g. S^T = K*Q^T.
// ---------------------------------------------------------------------------
__global__ __launch_bounds__(256) void attn3(
    const bf16* __restrict__ Q, const bf16* __restrict__ LK,
    const bf16* __restrict__ LVt, bf16* __restrict__ O)
{
    __shared__ __align__(16) bf16 Ks[64 * 32];   // [s][d], chunk q^((row>>1)&3)
    __shared__ __align__(16) bf16 Vs[32 * 64];   // [d][s], chunk q^(row&7)
    __shared__ __align__(16) bf16 Ps[64 * 72];   // [t][s], LD=72, wave-private

    const int tid  = threadIdx.x;
    const int lane = tid & 63;
    const int w    = tid >> 6;
    const int r16  = lane & 15;
    const int q8   = lane >> 4;
    const int hg = blockIdx.y, h = hg >> 2, g = hg & 3;
    const int t0 = blockIdx.x * 64;

    // loop-invariant Q B-fragment: B[n=t][k=d]
    const bf16x8 qb = *(const bf16x8*)(Q + (size_t)(t0 + w * 16 + r16) * 2048
                                       + h * 128 + g * 32 + q8 * 8);

    // K staging: thread -> local row kr=tid>>2, swizzled global chunk
    const int kr = tid >> 2;
    const int kq = (tid & 3) ^ ((tid >> 3) & 3);
    const bf16* kg = LK + (size_t)kr * 512 + h * 32 + kq * 8;
    // V staging: local row vd=tid>>3, swizzled global chunk (row 128B coalesced)
    const int vd = tid >> 3;
    const int vq = (tid & 7) ^ ((tid >> 3) & 7);
    const bf16* vg = LVt + (size_t)(h * 32 + vd) * 2048 + vq * 8;

    const int ksw = (r16 >> 1) & 3;   // K read swizzle
    const int vsw = r16 & 7;          // V read swizzle

    f32x4 o_acc[2] = {};
    float lsum = 0.f;
    const float Cc = 0.08838834764831845f * 1.4426950408889634f;  // 1/sqrt(128)*log2(e)
    const f32x4 z = {0.f, 0.f, 0.f, 0.f};

    for (int sb = 0; sb < 2048; sb += 64) {
        gload_lds16(kg + (size_t)sb * 512, &Ks[tid * 8]);
        gload_lds16(vg + sb,               &Vs[tid * 8]);
        __syncthreads();

        // S^T tile: A = K rows (m=s), B = Q (n=t)
        f32x4 s[4];
#pragma unroll
        for (int c = 0; c < 4; ++c) {
            bf16x8 kb = *(const bf16x8*)&Ks[(c * 16 + r16) * 32 + (q8 ^ ksw) * 8];
            s[c] = __builtin_amdgcn_mfma_f32_16x16x32_bf16(kb, qb, z, 0, 0, 0);
        }
        // lane holds S[t=w*16+r16][s=c*16+q8*4+i] -> exp -> packed b64 write
#pragma unroll
        for (int c = 0; c < 4; ++c) {
            bf16x4 pk;
#pragma unroll
            for (int i = 0; i < 4; ++i) {
                float p = exp2f(s[c][i] * Cc);
                lsum += p;
                pk[i] = (bf16)p;
            }
            *(bf16x4*)&Ps[(w * 16 + r16) * 72 + c * 16 + q8 * 4] = pk;
        }
        // O += P @ V^T : A = P (wave-private strip), B = Vs rows (n=d)
#pragma unroll
        for (int kk = 0; kk < 2; ++kk) {
            bf16x8 ap = *(const bf16x8*)&Ps[(w * 16 + r16) * 72 + kk * 32 + q8 * 8];
#pragma unroll
            for (int ct = 0; ct < 2; ++ct) {
                bf16x8 vb = *(const bf16x8*)&Vs[(ct * 16 + r16) * 64
                                                + (((kk * 4 + q8) ^ vsw) * 8)];
                o_acc[ct] = __builtin_amdgcn_mfma_f32_16x16x32_bf16(ap, vb, o_acc[ct], 0, 0, 0);
            }
        }
        __syncthreads();
    }

    // row-sum for t = w*16+r16 (reduce over q8 groups), then redistribute to
    // C-layout rows t_local = q8*4+i
    lsum += __shfl_xor(lsum, 16);
    lsum += __shfl_xor(lsum, 32);
    float ls[4];
#pragma unroll
    for (int i = 0; i < 4; ++i) ls[i] = __shfl(lsum, q8 * 4 + i);

#pragma unroll
    for (int ct = 0; ct < 2; ++ct)
#pragma unroll
        for (int i = 0; i < 4; ++i) {
            float o = o_acc[ct][i] / ls[i];
            int t = t0 + w * 16 + q8 * 4 + i;
            int d = ct * 16 + r16;
            O[(size_t)t * 2048 + h * 128 + g * 32 + d] = (bf16)o;
        }
}

// ---------------------------------------------------------------------------
// Contract (verified R6 bench): inputs fp32, output fp32.
// ---------------------------------------------------------------------------
extern "C" void kernel_launch(void* const* d_in, const int* in_sizes, int n_in,
                              void* d_out, int out_size, void* d_ws, size_t ws_size,
                              hipStream_t stream) {
    const float* x   = (const float*)d_in[0];
    const float* Wq  = (const float*)d_in[1];
    // d_in[2]=Wk, d_in[3]=Wv: computed-but-unused in the reference -> skipped
    const float* Wlk = (const float*)d_in[4];
    const float* Wlv = (const float*)d_in[5];
    const float* Wo  = (const float*)d_in[6];
    float* out = (float*)d_out;

    const size_t M4 = 4194304, M1 = 1048576;
    const size_t need_fast = (M1 + M1 + M4 + M4 + M1 + M1) * 2;  // 24 MB

    if (ws_size >= need_fast) {
        bf16* xb   = (bf16*)d_out;      // d_out scratch: dead before out_kernel writes
        bf16* Wqb  = xb + M4;
        bf16* p    = (bf16*)d_ws;
        bf16* Wlkb = p; p += M1;
        bf16* Wlvb = p; p += M1;
        bf16* Wob  = p; p += M4;
        bf16* Qp   = p; p += M4;
        bf16* LKp  = p; p += M1;
        bf16* LVt  = p;
        bf16* ATT  = Qp;                // alias: attn block reads its own Q cells first

        cvt5<<<dim3(2048, 5), 256, 0, stream>>>(x, Wq, Wlk, Wlv, Wo,
                                                xb, Wqb, Wlkb, Wlvb, Wob);
        proj_kernel_t<false><<<dim3(24, 16), 256, 0, stream>>>(xb, Wqb, Wlkb, Wlvb,
                                                               Qp, LKp, LVt);
        attn3<<<dim3(32, 64), 256, 0, stream>>>(Qp, LKp, LVt, ATT);
        out_kernel_t<false><<<dim3(16, 16), 256, 0, stream>>>(ATT, Wob, out);
    } else {
        bf16* Qp  = (bf16*)d_ws;
        bf16* LKp = Qp + M4;
        bf16* LVt = LKp + M1;
        bf16* ATT = Qp;

        proj_kernel_t<true><<<dim3(24, 16), 256, 0, stream>>>(x, Wq, Wlk, Wlv,
                                                              Qp, LKp, LVt);
        attn3<<<dim3(32, 64), 256, 0, stream>>>(Qp, LKp, LVt, ATT);
        out_kernel_t<true><<<dim3(16, 16), 256, 0, stream>>>(ATT, Wo, out);
    }
}